// Round 2
// baseline (4881.021 us; speedup 1.0000x reference)
//
#include <hip/hip_runtime.h>
#include <cstdint>

typedef __bf16 bf16;
typedef __bf16 bf16x8 __attribute__((ext_vector_type(8)));
typedef __bf16 bf16x4 __attribute__((ext_vector_type(4)));
typedef float f32x4 __attribute__((ext_vector_type(4)));

static_assert(sizeof(bf16) == 2, "bf16 size");

constexpr int LAYERS = 6;
constexpr int BATCH  = 8;
constexpr int TDEC   = 1024;
constexpr int SENC   = 1024;
constexpr int EMB    = 1024;
constexpr int NH     = 16;
constexpr int FFN    = 4096;
constexpr int MTOK   = BATCH * TDEC;  // 8192

typedef __attribute__((address_space(1))) void gvoid;
typedef __attribute__((address_space(3))) void lvoid;

// async global->LDS, 16B per lane; LDS dest = wave-uniform base + lane*16
__device__ __forceinline__ void gload16(const void* g, void* l) {
  __builtin_amdgcn_global_load_lds((gvoid*)(uintptr_t)g,
                                   (lvoid*)(uint32_t)(uintptr_t)l,
                                   16, 0, 0);
}

__device__ __forceinline__ f32x4 mfma_16x16x32(bf16x8 a, bf16x8 b, f32x4 c) {
  return __builtin_amdgcn_mfma_f32_16x16x32_bf16(a, b, c, 0, 0, 0);
}

// ---------------- elementwise: fp32 -> bf16 convert ----------------
__global__ void k_cvt(const float* __restrict__ in, bf16* __restrict__ outp, int n4) {
  int i = blockIdx.x * 256 + threadIdx.x;
  if (i < n4) {
    float4 v = ((const float4*)in)[i];
    bf16x4 o;
    o[0] = (bf16)v.x; o[1] = (bf16)v.y; o[2] = (bf16)v.z; o[3] = (bf16)v.w;
    ((bf16x4*)outp)[i] = o;
  }
}

// ---------------- transpose fp32 [R,C] -> bf16 [C,R] ----------------
__launch_bounds__(256)
__global__ void k_transpose(const float* __restrict__ in, bf16* __restrict__ outp,
                            int R, int C) {
  __shared__ float tile[32][33];
  const int tx = threadIdx.x, ty = threadIdx.y;
  const int r0 = blockIdx.y * 32, c0 = blockIdx.x * 32;
#pragma unroll
  for (int i = 0; i < 32; i += 8)
    tile[ty + i][tx] = in[(size_t)(r0 + ty + i) * C + c0 + tx];
  __syncthreads();
#pragma unroll
  for (int i = 0; i < 32; i += 8)
    outp[(size_t)(c0 + ty + i) * R + r0 + tx] = (bf16)tile[tx][ty + i];
}

// batched 4-matrix transpose (same shape), select by blockIdx.z
__launch_bounds__(256)
__global__ void k_transpose4(const float* __restrict__ s0, const float* __restrict__ s1,
                             const float* __restrict__ s2, const float* __restrict__ s3,
                             bf16* __restrict__ d0, bf16* __restrict__ d1,
                             bf16* __restrict__ d2, bf16* __restrict__ d3,
                             int R, int C) {
  const int z = blockIdx.z;
  const float* in = (z == 0) ? s0 : (z == 1) ? s1 : (z == 2) ? s2 : s3;
  bf16* outp      = (z == 0) ? d0 : (z == 1) ? d1 : (z == 2) ? d2 : d3;
  __shared__ float tile[32][33];
  const int tx = threadIdx.x, ty = threadIdx.y;
  const int r0 = blockIdx.y * 32, c0 = blockIdx.x * 32;
#pragma unroll
  for (int i = 0; i < 32; i += 8)
    tile[ty + i][tx] = in[(size_t)(r0 + ty + i) * C + c0 + tx];
  __syncthreads();
#pragma unroll
  for (int i = 0; i < 32; i += 8)
    outp[(size_t)(c0 + ty + i) * R + r0 + tx] = (bf16)tile[tx][ty + i];
}

// ---------------- LayerNorm fp32 -> bf16, row = 1024 ----------------
__launch_bounds__(256)
__global__ void k_layernorm(const float* __restrict__ x, const float* __restrict__ w,
                            const float* __restrict__ bb, bf16* __restrict__ outp) {
  const int row = blockIdx.x;
  const int t = threadIdx.x;
  const float4 v = ((const float4*)(x + (size_t)row * EMB))[t];
  float s = v.x + v.y + v.z + v.w;
  __shared__ float red[4];
#pragma unroll
  for (int off = 32; off > 0; off >>= 1) s += __shfl_down(s, off, 64);
  if ((t & 63) == 0) red[t >> 6] = s;
  __syncthreads();
  const float mean = (red[0] + red[1] + red[2] + red[3]) * (1.0f / EMB);
  const float dx = v.x - mean, dy = v.y - mean, dz = v.z - mean, dw = v.w - mean;
  float ss = dx * dx + dy * dy + dz * dz + dw * dw;
  __syncthreads();
#pragma unroll
  for (int off = 32; off > 0; off >>= 1) ss += __shfl_down(ss, off, 64);
  if ((t & 63) == 0) red[t >> 6] = ss;
  __syncthreads();
  const float var = (red[0] + red[1] + red[2] + red[3]) * (1.0f / EMB);
  const float rstd = rsqrtf(var + 1e-5f);
  const float4 wv = ((const float4*)w)[t];
  const float4 bv = ((const float4*)bb)[t];
  bf16x4 o;
  o[0] = (bf16)(dx * rstd * wv.x + bv.x);
  o[1] = (bf16)(dy * rstd * wv.y + bv.y);
  o[2] = (bf16)(dz * rstd * wv.z + bv.z);
  o[3] = (bf16)(dw * rstd * wv.w + bv.w);
  *(bf16x4*)(outp + (size_t)row * EMB + t * 4) = o;
}

// ---------------- GEMM: C[M,N] = A[M,K] @ Bt[N,K]^T, output ld = ldc ----------
// EPI 0: bf16 out. EPI 1: bf16 out = gelu(acc + bias). EPI 2: fp32 out = res + acc + bias.
// T1 XCD swizzle: contiguous block-id chunk per XCD (bijective when nwg%8==0).
template <int EPI>
__launch_bounds__(256)
__global__ void k_gemm(const bf16* __restrict__ A, const bf16* __restrict__ Bt,
                       int M, int N, int K, int ldc,
                       bf16* __restrict__ outb, float* __restrict__ outf,
                       const float* __restrict__ res, const float* __restrict__ bias) {
  __shared__ __align__(16) bf16 sA[128 * 32];
  __shared__ __align__(16) bf16 sB[128 * 32];
  const int tid = threadIdx.x;
  const int wave = tid >> 6, lane = tid & 63;
  const int quad = lane >> 4, l16 = lane & 15;
  const int wm = wave >> 1, wn = wave & 1;

  // XCD-aware block swizzle
  int bid = blockIdx.y * gridDim.x + blockIdx.x;
  const int nwg = gridDim.x * gridDim.y;
  if ((nwg & 7) == 0) {
    const int q = nwg >> 3;
    bid = (bid & 7) * q + (bid >> 3);
  }
  const int bn = bid % gridDim.x;
  const int bm = bid / gridDim.x;

  f32x4 acc[4][4] = {};

  const int srow = wave * 16 + (lane >> 2);
  const int scol = (lane & 3) * 8;
  const bf16* Ag = A  + (size_t)(bm * 128 + srow) * K + scol;
  const bf16* Bg = Bt + (size_t)(bn * 128 + srow) * K + scol;
  bf16* sA0 = &sA[(wave * 16) * 32];
  bf16* sA1 = &sA[(wave * 16 + 64) * 32];
  bf16* sB0 = &sB[(wave * 16) * 32];
  bf16* sB1 = &sB[(wave * 16 + 64) * 32];

  const int nk = K >> 5;
  for (int kt = 0; kt < nk; ++kt) {
    gload16(Ag, sA0);
    gload16(Ag + (size_t)64 * K, sA1);
    gload16(Bg, sB0);
    gload16(Bg + (size_t)64 * K, sB1);
    Ag += 32; Bg += 32;
    __syncthreads();
    bf16x8 af[4], bfv[4];
    const bf16* pa = &sA[(wm * 64 + l16) * 32 + quad * 8];
    const bf16* pb = &sB[(wn * 64 + l16) * 32 + quad * 8];
#pragma unroll
    for (int i = 0; i < 4; ++i) af[i] = *(const bf16x8*)(pa + i * 16 * 32);
#pragma unroll
    for (int i = 0; i < 4; ++i) bfv[i] = *(const bf16x8*)(pb + i * 16 * 32);
#pragma unroll
    for (int i = 0; i < 4; ++i)
#pragma unroll
      for (int j = 0; j < 4; ++j)
        acc[i][j] = mfma_16x16x32(af[i], bfv[j], acc[i][j]);
    __syncthreads();
  }

  const int row0 = bm * 128 + wm * 64;
  const int col0 = bn * 128 + wn * 64;
#pragma unroll
  for (int j = 0; j < 4; ++j) {
    const int c = col0 + j * 16 + l16;
    const float bv = (EPI >= 1) ? bias[c] : 0.0f;
#pragma unroll
    for (int i = 0; i < 4; ++i) {
#pragma unroll
      for (int r = 0; r < 4; ++r) {
        const size_t rr = (size_t)(row0 + i * 16 + quad * 4 + r);
        float v = acc[i][j][r];
        if (EPI == 0) {
          outb[rr * ldc + c] = (bf16)v;
        } else if (EPI == 1) {
          v += bv;
          // gelu tanh-approx: 0.5v(1+tanh(u)) == v / (1 + exp2(-2u*log2e))
          const float u = 0.7978845608028654f * (v + 0.044715f * v * v * v);
          const float g = v / (1.0f + exp2f(u * -2.8853900817779268f));
          outb[rr * ldc + c] = (bf16)g;
        } else {
          outf[rr * ldc + c] = res[rr * ldc + c] + v + bv;
        }
      }
    }
  }
}

// ---------------- flash attention v2 ----------------
// 128 q-rows / block (wave w: rows q0+32w..+31, two 16-row m-subtiles),
// 64-key tiles. sK XOR-swizzled (gload16-compatible), sVt/sP stride-72.
// Q/K/V read from a common [rows, ld] buffer (fused QKV) at given column bases.
// T1 swizzle: each XCD owns gridDim.y/8 whole heads (K/V panel stays in its L2).
// grid: (TQ/128, B*NH), block 256.
template <bool CAUSAL>
__launch_bounds__(256)
__global__ void k_attn(const bf16* __restrict__ Q, const bf16* __restrict__ Kg,
                       const bf16* __restrict__ Vg, bf16* __restrict__ Og,
                       int TQ, int TK, int ld) {
  __shared__ __align__(16) bf16 sK[64 * 64];    // [key][d], 16B chunks XOR-swizzled
  __shared__ __align__(16) bf16 sVt[64 * 72];   // [d][key], stride 72
  __shared__ __align__(16) bf16 sP[4][32 * 72]; // per wave, [q_local][key], stride 72
  const int tid = threadIdx.x;
  const int wave = tid >> 6, lane = tid & 63;
  const int quad = lane >> 4, l16 = lane & 15;

  // XCD-aware remap: cluster all q-tiles of a head on one XCD
  int bx = blockIdx.x, by = blockIdx.y;
  {
    const int nwg = gridDim.x * gridDim.y;
    if ((nwg & 7) == 0 && (gridDim.y & 7) == 0) {
      const int d = by * gridDim.x + bx;
      const int xcd = d & 7, idx = d >> 3;
      const int hpx = gridDim.y >> 3;  // heads per XCD
      by = xcd * hpx + idx / gridDim.x;
      bx = idx % gridDim.x;
    }
  }
  const int b = by >> 4;   // NH == 16
  const int h = by & 15;
  const int qt = CAUSAL ? (gridDim.x - 1 - bx) : bx;
  const int q0 = qt * 128;
  const int qw = q0 + wave * 32;

  const bf16* Qbase = Q + (size_t)(b * TQ) * ld + h * 64;
  const bf16* Kbase = Kg + (size_t)(b * TK) * ld + h * 64;
  const bf16* Vbase = Vg + (size_t)(b * TK) * ld + h * 64;

  // Q fragments: aq[m][c] covers rows qw+m*16+l16, d = c*32 + quad*8 .. +7
  bf16x8 aq[2][2];
#pragma unroll
  for (int m = 0; m < 2; ++m) {
    const bf16* qp = Qbase + (size_t)(qw + m * 16 + l16) * ld + quad * 8;
    aq[m][0] = *(const bf16x8*)(qp);
    aq[m][1] = *(const bf16x8*)(qp + 32);
  }

  f32x4 oacc[2][4] = {};
  float m_[2][4], l_[2][4];
#pragma unroll
  for (int m = 0; m < 2; ++m)
#pragma unroll
    for (int r = 0; r < 4; ++r) { m_[m][r] = -1e30f; l_[m][r] = 0.0f; }

  const int srow = lane >> 3;      // 0..7 (row within 8-row staging group)
  const int schunk = lane & 7;     // physical 16B chunk
  bf16* sPw = &sP[wave][0];

  const float sc = 0.125f * 1.44269504088896f;  // 1/sqrt(64) * log2(e)
  const int nj = CAUSAL ? (q0 >> 6) + 2 : (TK >> 6);

  for (int j = 0; j < nj; ++j) {
    const int k0 = j * 64;
    // ---- stage K: 64 rows x 128B, chunk c stored at c^(row&7) ----
#pragma unroll
    for (int r2 = 0; r2 < 2; ++r2) {
      const int rowt = (wave + 4 * r2) * 8 + srow;
      const int gchunk = schunk ^ (rowt & 7);
      gload16(Kbase + (size_t)(k0 + rowt) * ld + gchunk * 8,
              &sK[(wave + 4 * r2) * 8 * 64]);
    }
    // ---- stage V^T: wave handles d-chunk (wave+4r2), keys = lane ----
#pragma unroll
    for (int r2 = 0; r2 < 2; ++r2) {
      const int cv = wave + 4 * r2;
      const bf16x8 vv = *(const bf16x8*)(Vbase + (size_t)(k0 + lane) * ld + cv * 8);
#pragma unroll
      for (int e = 0; e < 8; ++e) sVt[(cv * 8 + e) * 72 + lane] = vv[e];
    }
    __syncthreads();

    const bool active = !CAUSAL || (k0 <= qw + 31);
    if (active) {
#pragma unroll
      for (int m = 0; m < 2; ++m) {
        // ---- QK^T: scores s[kt][r] = S[row=m*16+quad*4+r][key=kt*16+l16] ----
        f32x4 s[4];
#pragma unroll
        for (int kt = 0; kt < 4; ++kt) {
          const int krow = kt * 16 + l16;
          const int p0 = (quad ^ (l16 & 7)) * 8;
          const int p1 = ((quad + 4) ^ (l16 & 7)) * 8;
          const bf16x8 bk0 = *(const bf16x8*)(&sK[krow * 64 + p0]);
          const bf16x8 bk1 = *(const bf16x8*)(&sK[krow * 64 + p1]);
          f32x4 z = {};
          z = mfma_16x16x32(aq[m][0], bk0, z);
          z = mfma_16x16x32(aq[m][1], bk1, z);
          s[kt] = z;
        }
        // ---- causal mask (raw domain) + row max ----
        float rowmax[4] = {-1e30f, -1e30f, -1e30f, -1e30f};
#pragma unroll
        for (int kt = 0; kt < 4; ++kt) {
          const int key = k0 + kt * 16 + l16;
#pragma unroll
          for (int r = 0; r < 4; ++r) {
            if (CAUSAL && key > qw + m * 16 + quad * 4 + r) s[kt][r] = -1e30f;
            rowmax[r] = fmaxf(rowmax[r], s[kt][r]);
          }
        }
#pragma unroll
        for (int off = 1; off < 16; off <<= 1)
#pragma unroll
          for (int r = 0; r < 4; ++r)
            rowmax[r] = fmaxf(rowmax[r], __shfl_xor(rowmax[r], off, 64));
        float alpha[4], nms[4], rs[4];
#pragma unroll
        for (int r = 0; r < 4; ++r) {
          const float mn = fmaxf(m_[m][r], rowmax[r]);
          alpha[r] = exp2f((m_[m][r] - mn) * sc);
          m_[m][r] = mn;
          nms[r] = -mn * sc;
          rs[r] = 0.0f;
        }
        // ---- P = exp2(s*sc - m*sc), row sums, write to sP ----
#pragma unroll
        for (int kt = 0; kt < 4; ++kt)
#pragma unroll
          for (int r = 0; r < 4; ++r) {
            const float pv = exp2f(fmaf(s[kt][r], sc, nms[r]));
            rs[r] += pv;
            sPw[(m * 16 + quad * 4 + r) * 72 + kt * 16 + l16] = (bf16)pv;
          }
#pragma unroll
        for (int off = 1; off < 16; off <<= 1)
#pragma unroll
          for (int r = 0; r < 4; ++r)
            rs[r] += __shfl_xor(rs[r], off, 64);
#pragma unroll
        for (int r = 0; r < 4; ++r) {
          l_[m][r] = l_[m][r] * alpha[r] + rs[r];
#pragma unroll
          for (int dt = 0; dt < 4; ++dt) oacc[m][dt][r] *= alpha[r];
        }
        // ---- PV ----
        const bf16x8 ap0 = *(const bf16x8*)(&sPw[(m * 16 + l16) * 72 + quad * 8]);
        const bf16x8 ap1 = *(const bf16x8*)(&sPw[(m * 16 + l16) * 72 + 32 + quad * 8]);
#pragma unroll
        for (int dt = 0; dt < 4; ++dt) {
          const bf16x8 bv0 = *(const bf16x8*)(&sVt[(dt * 16 + l16) * 72 + quad * 8]);
          const bf16x8 bv1 = *(const bf16x8*)(&sVt[(dt * 16 + l16) * 72 + 32 + quad * 8]);
          oacc[m][dt] = mfma_16x16x32(ap0, bv0, oacc[m][dt]);
          oacc[m][dt] = mfma_16x16x32(ap1, bv1, oacc[m][dt]);
        }
      }
    }
    __syncthreads();
  }

#pragma unroll
  for (int m = 0; m < 2; ++m)
#pragma unroll
    for (int r = 0; r < 4; ++r) {
      const float inv = 1.0f / l_[m][r];
      bf16* op = Og + (size_t)(b * TQ + qw + m * 16 + quad * 4 + r) * EMB + h * 64;
#pragma unroll
      for (int dt = 0; dt < 4; ++dt)
        op[dt * 16 + l16] = (bf16)(oacc[m][dt][r] * inv);
    }
}

// ---------------- host orchestration ----------------
extern "C" void kernel_launch(void* const* d_in, const int* in_sizes, int n_in,
                              void* d_out, int out_size, void* d_ws, size_t ws_size,
                              hipStream_t stream) {
  const float* enc  = (const float*)d_in[0];
  const float* dec  = (const float*)d_in[1];
  const float* ln1w = (const float*)d_in[2];
  const float* ln1b = (const float*)d_in[3];
  const float* ln2w = (const float*)d_in[4];
  const float* ln2b = (const float*)d_in[5];
  const float* ln3w = (const float*)d_in[6];
  const float* ln3b = (const float*)d_in[7];
  const float* Wq_s = (const float*)d_in[8];
  const float* Wk_s = (const float*)d_in[9];
  const float* Wv_s = (const float*)d_in[10];
  const float* Wo_s = (const float*)d_in[11];
  const float* bo_s = (const float*)d_in[12];
  const float* Wq_c = (const float*)d_in[13];
  const float* Wk_c = (const float*)d_in[14];
  const float* Wv_c = (const float*)d_in[15];
  const float* Wo_c = (const float*)d_in[16];
  const float* bo_c = (const float*)d_in[17];
  const float* W1   = (const float*)d_in[18];
  const float* b1   = (const float*)d_in[19];
  const float* W2   = (const float*)d_in[20];
  const float* b2   = (const float*)d_in[21];
  float* out = (float*)d_out;

  char* p = (char*)d_ws;
  auto take = [&](size_t bytes) {
    char* r = p;
    p += (bytes + 255) & ~(size_t)255;
    return (void*)r;
  };
  bf16* wqkvT = (bf16*)take((size_t)3 * EMB * EMB * 2);  // fused [3E, E] (q|k|v rows)
  bf16* woT   = (bf16*)take((size_t)EMB * EMB * 2);
  bf16* w1T   = (bf16*)take((size_t)EMB * FFN * 2);
  bf16* w2T   = (bf16*)take((size_t)FFN * EMB * 2);
  bf16* encb  = (bf16*)take((size_t)BATCH * SENC * EMB * 2);
  float* xbuf = (float*)take((size_t)MTOK * EMB * 4);
  bf16* nx    = (bf16*)take((size_t)MTOK * EMB * 2);
  bf16* qkvb  = (bf16*)take((size_t)MTOK * 3 * EMB * 2); // fused [M, 3E] (q|k|v cols)
  bf16* ab    = (bf16*)take((size_t)MTOK * EMB * 2);
  bf16* hb    = (bf16*)take((size_t)MTOK * FFN * 2);
  if ((size_t)((char*)p - (char*)d_ws) > ws_size) return;  // ws too small: fail loudly

  const int LD3 = 3 * EMB;

  // encoder -> bf16 (once); x = decoder_input
  {
    const int n4 = BATCH * SENC * EMB / 4;
    k_cvt<<<(n4 + 255) / 256, 256, 0, stream>>>(enc, encb, n4);
  }
  hipMemcpyAsync(xbuf, dec, (size_t)MTOK * EMB * 4, hipMemcpyDeviceToDevice, stream);

  auto trans = [&](const float* w, bf16* wt, int R, int C) {
    k_transpose<<<dim3(C / 32, R / 32), dim3(32, 8), 0, stream>>>(w, wt, R, C);
  };
  // 4 same-shape EMBxEMB weights in one launch
  auto trans4 = [&](const float* s0, const float* s1, const float* s2, const float* s3,
                    bf16* d0, bf16* d1, bf16* d2, bf16* d3) {
    k_transpose4<<<dim3(EMB / 32, EMB / 32, 4), dim3(32, 8), 0, stream>>>(
        s0, s1, s2, s3, d0, d1, d2, d3, EMB, EMB);
  };
  auto gemm0 = [&](const bf16* Ap, const bf16* Btp, bf16* op, int M, int N, int K,
                   int ldc) {
    k_gemm<0><<<dim3(N / 128, M / 128), 256, 0, stream>>>(Ap, Btp, M, N, K, ldc, op,
                                                          nullptr, nullptr, nullptr);
  };
  auto gemm_gelu = [&](const bf16* Ap, const bf16* Btp, bf16* op, const float* bi,
                       int M, int N, int K) {
    k_gemm<1><<<dim3(N / 128, M / 128), 256, 0, stream>>>(Ap, Btp, M, N, K, N, op,
                                                          nullptr, nullptr, bi);
  };
  auto gemm_res = [&](const bf16* Ap, const bf16* Btp, float* op, const float* rs,
                      const float* bi, int M, int N, int K) {
    k_gemm<2><<<dim3(N / 128, M / 128), 256, 0, stream>>>(Ap, Btp, M, N, K, N, nullptr,
                                                          op, rs, bi);
  };

  for (int l = 0; l < LAYERS; ++l) {
    const size_t wofs = (size_t)l * EMB * EMB;
    // ---- self attention ----
    k_layernorm<<<MTOK, 256, 0, stream>>>(xbuf, ln1w + l * EMB, ln1b + l * EMB, nx);
    trans4(Wq_s + wofs, Wk_s + wofs, Wv_s + wofs, Wo_s + wofs,
           wqkvT, wqkvT + (size_t)EMB * EMB, wqkvT + (size_t)2 * EMB * EMB, woT);
    // fused QKV projection: [M, 3E]
    gemm0(nx, wqkvT, qkvb, MTOK, 3 * EMB, EMB, LD3);
    k_attn<true><<<dim3(TDEC / 128, BATCH * NH), 256, 0, stream>>>(
        qkvb, qkvb + EMB, qkvb + 2 * EMB, ab, TDEC, TDEC, LD3);
    gemm_res(ab, woT, xbuf, xbuf, bo_s + l * EMB, MTOK, EMB, EMB);

    // ---- cross attention ----
    k_layernorm<<<MTOK, 256, 0, stream>>>(xbuf, ln2w + l * EMB, ln2b + l * EMB, nx);
    trans4(Wq_c + wofs, Wk_c + wofs, Wv_c + wofs, Wo_c + wofs,
           wqkvT, wqkvT + (size_t)EMB * EMB, wqkvT + (size_t)2 * EMB * EMB, woT);
    // Q over nx; fused K|V over encoder
    gemm0(nx, wqkvT, qkvb, MTOK, EMB, EMB, LD3);
    gemm0(encb, wqkvT + (size_t)EMB * EMB, qkvb + EMB, BATCH * SENC, 2 * EMB, EMB, LD3);
    k_attn<false><<<dim3(TDEC / 128, BATCH * NH), 256, 0, stream>>>(
        qkvb, qkvb + EMB, qkvb + 2 * EMB, ab, TDEC, SENC, LD3);
    gemm_res(ab, woT, xbuf, xbuf, bo_c + l * EMB, MTOK, EMB, EMB);

    // ---- FFN ----
    k_layernorm<<<MTOK, 256, 0, stream>>>(xbuf, ln3w + l * EMB, ln3b + l * EMB, nx);
    trans(W1 + (size_t)l * EMB * FFN, w1T, EMB, FFN);
    trans(W2 + (size_t)l * FFN * EMB, w2T, FFN, EMB);
    gemm_gelu(nx, w1T, hb, b1 + (size_t)l * FFN, MTOK, FFN, EMB);
    float* fout = (l == LAYERS - 1) ? out : xbuf;
    gemm_res(hb, w2T, fout, xbuf, b2 + (size_t)l * EMB, MTOK, EMB, FFN);
  }
}

// Round 3
// 4593.648 us; speedup vs baseline: 1.0626x; 1.0626x over previous
//
#include <hip/hip_runtime.h>
#include <cstdint>

typedef __bf16 bf16;
typedef __bf16 bf16x8 __attribute__((ext_vector_type(8)));
typedef __bf16 bf16x4 __attribute__((ext_vector_type(4)));
typedef float f32x4 __attribute__((ext_vector_type(4)));

static_assert(sizeof(bf16) == 2, "bf16 size");

constexpr int LAYERS = 6;
constexpr int BATCH  = 8;
constexpr int TDEC   = 1024;
constexpr int SENC   = 1024;
constexpr int EMB    = 1024;
constexpr int NH     = 16;
constexpr int FFN    = 4096;
constexpr int MTOK   = BATCH * TDEC;  // 8192

typedef __attribute__((address_space(1))) void gvoid;
typedef __attribute__((address_space(3))) void lvoid;

// async global->LDS, 16B per lane; LDS dest = wave-uniform base + lane*16
__device__ __forceinline__ void gload16(const void* g, void* l) {
  __builtin_amdgcn_global_load_lds((gvoid*)(uintptr_t)g,
                                   (lvoid*)(uint32_t)(uintptr_t)l,
                                   16, 0, 0);
}

__device__ __forceinline__ f32x4 mfma_16x16x32(bf16x8 a, bf16x8 b, f32x4 c) {
  return __builtin_amdgcn_mfma_f32_16x16x32_bf16(a, b, c, 0, 0, 0);
}

// ---------------- elementwise: fp32 -> bf16 convert ----------------
__global__ void k_cvt(const float* __restrict__ in, bf16* __restrict__ outp, int n4) {
  int i = blockIdx.x * 256 + threadIdx.x;
  if (i < n4) {
    float4 v = ((const float4*)in)[i];
    bf16x4 o;
    o[0] = (bf16)v.x; o[1] = (bf16)v.y; o[2] = (bf16)v.z; o[3] = (bf16)v.w;
    ((bf16x4*)outp)[i] = o;
  }
}

// ---------------- transpose fp32 [R,C] -> bf16 [C,R] ----------------
__launch_bounds__(256)
__global__ void k_transpose(const float* __restrict__ in, bf16* __restrict__ outp,
                            int R, int C) {
  __shared__ float tile[32][33];
  const int tx = threadIdx.x, ty = threadIdx.y;
  const int r0 = blockIdx.y * 32, c0 = blockIdx.x * 32;
#pragma unroll
  for (int i = 0; i < 32; i += 8)
    tile[ty + i][tx] = in[(size_t)(r0 + ty + i) * C + c0 + tx];
  __syncthreads();
#pragma unroll
  for (int i = 0; i < 32; i += 8)
    outp[(size_t)(c0 + ty + i) * R + r0 + tx] = (bf16)tile[tx][ty + i];
}

// batched 4-matrix transpose (same shape), select by blockIdx.z
__launch_bounds__(256)
__global__ void k_transpose4(const float* __restrict__ s0, const float* __restrict__ s1,
                             const float* __restrict__ s2, const float* __restrict__ s3,
                             bf16* __restrict__ d0, bf16* __restrict__ d1,
                             bf16* __restrict__ d2, bf16* __restrict__ d3,
                             int R, int C) {
  const int z = blockIdx.z;
  const float* in = (z == 0) ? s0 : (z == 1) ? s1 : (z == 2) ? s2 : s3;
  bf16* outp      = (z == 0) ? d0 : (z == 1) ? d1 : (z == 2) ? d2 : d3;
  __shared__ float tile[32][33];
  const int tx = threadIdx.x, ty = threadIdx.y;
  const int r0 = blockIdx.y * 32, c0 = blockIdx.x * 32;
#pragma unroll
  for (int i = 0; i < 32; i += 8)
    tile[ty + i][tx] = in[(size_t)(r0 + ty + i) * C + c0 + tx];
  __syncthreads();
#pragma unroll
  for (int i = 0; i < 32; i += 8)
    outp[(size_t)(c0 + ty + i) * R + r0 + tx] = (bf16)tile[tx][ty + i];
}

// ---------------- LayerNorm fp32 -> bf16, row = 1024 ----------------
__launch_bounds__(256)
__global__ void k_layernorm(const float* __restrict__ x, const float* __restrict__ w,
                            const float* __restrict__ bb, bf16* __restrict__ outp) {
  const int row = blockIdx.x;
  const int t = threadIdx.x;
  const float4 v = ((const float4*)(x + (size_t)row * EMB))[t];
  float s = v.x + v.y + v.z + v.w;
  __shared__ float red[4];
#pragma unroll
  for (int off = 32; off > 0; off >>= 1) s += __shfl_down(s, off, 64);
  if ((t & 63) == 0) red[t >> 6] = s;
  __syncthreads();
  const float mean = (red[0] + red[1] + red[2] + red[3]) * (1.0f / EMB);
  const float dx = v.x - mean, dy = v.y - mean, dz = v.z - mean, dw = v.w - mean;
  float ss = dx * dx + dy * dy + dz * dz + dw * dw;
  __syncthreads();
#pragma unroll
  for (int off = 32; off > 0; off >>= 1) ss += __shfl_down(ss, off, 64);
  if ((t & 63) == 0) red[t >> 6] = ss;
  __syncthreads();
  const float var = (red[0] + red[1] + red[2] + red[3]) * (1.0f / EMB);
  const float rstd = rsqrtf(var + 1e-5f);
  const float4 wv = ((const float4*)w)[t];
  const float4 bv = ((const float4*)bb)[t];
  bf16x4 o;
  o[0] = (bf16)(dx * rstd * wv.x + bv.x);
  o[1] = (bf16)(dy * rstd * wv.y + bv.y);
  o[2] = (bf16)(dz * rstd * wv.z + bv.z);
  o[3] = (bf16)(dw * rstd * wv.w + bv.w);
  *(bf16x4*)(outp + (size_t)row * EMB + t * 4) = o;
}

// ---------------- GEMM: C[M,N] = A[M,K] @ Bt[N,K]^T, output ld = ldc ----------
// EPI 0: bf16 out. EPI 1: bf16 out = gelu(acc + bias). EPI 2: fp32 out = res + acc + bias.
// T1 XCD swizzle: contiguous block-id chunk per XCD (bijective when nwg%8==0).
template <int EPI>
__launch_bounds__(256)
__global__ void k_gemm(const bf16* __restrict__ A, const bf16* __restrict__ Bt,
                       int M, int N, int K, int ldc,
                       bf16* __restrict__ outb, float* __restrict__ outf,
                       const float* __restrict__ res, const float* __restrict__ bias) {
  __shared__ __align__(16) bf16 sA[128 * 32];
  __shared__ __align__(16) bf16 sB[128 * 32];
  const int tid = threadIdx.x;
  const int wave = tid >> 6, lane = tid & 63;
  const int quad = lane >> 4, l16 = lane & 15;
  const int wm = wave >> 1, wn = wave & 1;

  // XCD-aware block swizzle
  int bid = blockIdx.y * gridDim.x + blockIdx.x;
  const int nwg = gridDim.x * gridDim.y;
  if ((nwg & 7) == 0) {
    const int q = nwg >> 3;
    bid = (bid & 7) * q + (bid >> 3);
  }
  const int bn = bid % gridDim.x;
  const int bm = bid / gridDim.x;

  f32x4 acc[4][4] = {};

  const int srow = wave * 16 + (lane >> 2);
  const int scol = (lane & 3) * 8;
  const bf16* Ag = A  + (size_t)(bm * 128 + srow) * K + scol;
  const bf16* Bg = Bt + (size_t)(bn * 128 + srow) * K + scol;
  bf16* sA0 = &sA[(wave * 16) * 32];
  bf16* sA1 = &sA[(wave * 16 + 64) * 32];
  bf16* sB0 = &sB[(wave * 16) * 32];
  bf16* sB1 = &sB[(wave * 16 + 64) * 32];

  const int nk = K >> 5;
  for (int kt = 0; kt < nk; ++kt) {
    gload16(Ag, sA0);
    gload16(Ag + (size_t)64 * K, sA1);
    gload16(Bg, sB0);
    gload16(Bg + (size_t)64 * K, sB1);
    Ag += 32; Bg += 32;
    __syncthreads();
    bf16x8 af[4], bfv[4];
    const bf16* pa = &sA[(wm * 64 + l16) * 32 + quad * 8];
    const bf16* pb = &sB[(wn * 64 + l16) * 32 + quad * 8];
#pragma unroll
    for (int i = 0; i < 4; ++i) af[i] = *(const bf16x8*)(pa + i * 16 * 32);
#pragma unroll
    for (int i = 0; i < 4; ++i) bfv[i] = *(const bf16x8*)(pb + i * 16 * 32);
#pragma unroll
    for (int i = 0; i < 4; ++i)
#pragma unroll
      for (int j = 0; j < 4; ++j)
        acc[i][j] = mfma_16x16x32(af[i], bfv[j], acc[i][j]);
    __syncthreads();
  }

  const int row0 = bm * 128 + wm * 64;
  const int col0 = bn * 128 + wn * 64;
#pragma unroll
  for (int j = 0; j < 4; ++j) {
    const int c = col0 + j * 16 + l16;
    const float bv = (EPI >= 1) ? bias[c] : 0.0f;
#pragma unroll
    for (int i = 0; i < 4; ++i) {
#pragma unroll
      for (int r = 0; r < 4; ++r) {
        const size_t rr = (size_t)(row0 + i * 16 + quad * 4 + r);
        float v = acc[i][j][r];
        if (EPI == 0) {
          outb[rr * ldc + c] = (bf16)v;
        } else if (EPI == 1) {
          v += bv;
          // gelu tanh-approx: 0.5v(1+tanh(u)) == v / (1 + exp2(-2u*log2e))
          const float u = 0.7978845608028654f * (v + 0.044715f * v * v * v);
          const float g = v / (1.0f + exp2f(u * -2.8853900817779268f));
          outb[rr * ldc + c] = (bf16)g;
        } else {
          outf[rr * ldc + c] = res[rr * ldc + c] + v + bv;
        }
      }
    }
  }
}

// ---------------- flash attention v2, pipelined ----------------
// 128 q-rows / block (wave w: rows q0+32w..+31, two 16-row m-subtiles),
// 64-key tiles, DOUBLE-BUFFERED K/V with one barrier per tile:
//   prefetch K[j+1] (gload16) + V[j+1] (regs) -> compute tile j -> write V regs
//   -> barrier. sK XOR-swizzled; sVt/sP stride-72.
// Row-sum of P computed by MFMA with constant ones B-fragment (no shuffles).
// Causal mask ops only on diagonal-straddling tiles.
// T1 swizzle: each XCD owns gridDim.y/8 whole heads.
// grid: (TQ/128, B*NH), block 256.
template <bool CAUSAL>
__launch_bounds__(256)
__global__ void k_attn(const bf16* __restrict__ Q, const bf16* __restrict__ Kg,
                       const bf16* __restrict__ Vg, bf16* __restrict__ Og,
                       int TQ, int TK, int ld) {
  __shared__ __align__(16) bf16 sK[2][64 * 64];   // [buf][key][d], XOR-swizzled
  __shared__ __align__(16) bf16 sVt[2][64 * 72];  // [buf][d][key], stride 72
  __shared__ __align__(16) bf16 sP[4][32 * 72];   // per wave, [q_local][key]
  const int tid = threadIdx.x;
  const int wave = tid >> 6, lane = tid & 63;
  const int quad = lane >> 4, l16 = lane & 15;

  // XCD-aware remap: cluster all q-tiles of a head on one XCD
  int bx = blockIdx.x, by = blockIdx.y;
  {
    const int nwg = gridDim.x * gridDim.y;
    if ((nwg & 7) == 0 && (gridDim.y & 7) == 0) {
      const int d = by * gridDim.x + bx;
      const int xcd = d & 7, idx = d >> 3;
      const int hpx = gridDim.y >> 3;  // heads per XCD
      by = xcd * hpx + idx / gridDim.x;
      bx = idx % gridDim.x;
    }
  }
  const int b = by >> 4;   // NH == 16
  const int h = by & 15;
  const int qt = CAUSAL ? (gridDim.x - 1 - bx) : bx;
  const int q0 = qt * 128;
  const int qw = q0 + wave * 32;

  const bf16* Qbase = Q + (size_t)(b * TQ) * ld + h * 64;
  const bf16* Kbase = Kg + (size_t)(b * TK) * ld + h * 64;
  const bf16* Vbase = Vg + (size_t)(b * TK) * ld + h * 64;

  // Q fragments: aq[m][c] covers rows qw+m*16+l16, d = c*32 + quad*8 .. +7
  bf16x8 aq[2][2];
#pragma unroll
  for (int m = 0; m < 2; ++m) {
    const bf16* qp = Qbase + (size_t)(qw + m * 16 + l16) * ld + quad * 8;
    aq[m][0] = *(const bf16x8*)(qp);
    aq[m][1] = *(const bf16x8*)(qp + 32);
  }

  bf16x8 vones;
#pragma unroll
  for (int e = 0; e < 8; ++e) vones[e] = (bf16)1.0f;

  f32x4 oacc[2][4] = {};
  float m_[2][4], l_[2][4];
#pragma unroll
  for (int m = 0; m < 2; ++m)
#pragma unroll
    for (int r = 0; r < 4; ++r) { m_[m][r] = -1e30f; l_[m][r] = 0.0f; }

  const int srow = lane >> 3;      // 0..7 (row within 8-row staging group)
  const int schunk = lane & 7;     // physical 16B chunk
  bf16* sPw = &sP[wave][0];

  const float sc = 0.125f * 1.44269504088896f;  // 1/sqrt(64) * log2(e)
  const int nj = CAUSAL ? (q0 >> 6) + 2 : (TK >> 6);

  // ---- prologue: stage tile 0 into buffer 0 ----
#pragma unroll
  for (int r2 = 0; r2 < 2; ++r2) {
    const int rowt = (wave + 4 * r2) * 8 + srow;
    const int gchunk = schunk ^ (rowt & 7);
    gload16(Kbase + (size_t)rowt * ld + gchunk * 8,
            &sK[0][(wave + 4 * r2) * 8 * 64]);
  }
#pragma unroll
  for (int r2 = 0; r2 < 2; ++r2) {
    const int cv = wave + 4 * r2;
    const bf16x8 vv = *(const bf16x8*)(Vbase + (size_t)lane * ld + cv * 8);
#pragma unroll
    for (int e = 0; e < 8; ++e) sVt[0][(cv * 8 + e) * 72 + lane] = vv[e];
  }
  __syncthreads();

  int cur = 0;
  for (int j = 0; j < nj; ++j) {
    const int nxt = cur ^ 1;
    const int k0 = j * 64;
    const bool pre = (j + 1 < nj);
    bf16x8 vpre[2];
    // ---- prefetch tile j+1: K -> sK[nxt] (async DMA), V -> regs ----
    if (pre) {
      const int k0n = k0 + 64;
#pragma unroll
      for (int r2 = 0; r2 < 2; ++r2) {
        const int rowt = (wave + 4 * r2) * 8 + srow;
        const int gchunk = schunk ^ (rowt & 7);
        gload16(Kbase + (size_t)(k0n + rowt) * ld + gchunk * 8,
                &sK[nxt][(wave + 4 * r2) * 8 * 64]);
      }
#pragma unroll
      for (int r2 = 0; r2 < 2; ++r2)
        vpre[r2] = *(const bf16x8*)(Vbase + (size_t)(k0n + lane) * ld +
                                    (wave + 4 * r2) * 8);
    }

    const bool active = !CAUSAL || (k0 <= qw + 31);
    if (active) {
#pragma unroll
      for (int m = 0; m < 2; ++m) {
        // ---- QK^T: scores s[kt][r] = S[row=m*16+quad*4+r][key=kt*16+l16] ----
        f32x4 s[4];
#pragma unroll
        for (int kt = 0; kt < 4; ++kt) {
          const int krow = kt * 16 + l16;
          const int p0 = (quad ^ (l16 & 7)) * 8;
          const int p1 = ((quad + 4) ^ (l16 & 7)) * 8;
          const bf16x8 bk0 = *(const bf16x8*)(&sK[cur][krow * 64 + p0]);
          const bf16x8 bk1 = *(const bf16x8*)(&sK[cur][krow * 64 + p1]);
          f32x4 z = {};
          z = mfma_16x16x32(aq[m][0], bk0, z);
          z = mfma_16x16x32(aq[m][1], bk1, z);
          s[kt] = z;
        }
        // ---- causal mask only on diagonal-straddling tiles + row max ----
        const int row_base = qw + m * 16;
        float rowmax[4] = {-1e30f, -1e30f, -1e30f, -1e30f};
        if (CAUSAL && (k0 + 63 > row_base)) {
#pragma unroll
          for (int kt = 0; kt < 4; ++kt) {
            const int key = k0 + kt * 16 + l16;
#pragma unroll
            for (int r = 0; r < 4; ++r) {
              if (key > row_base + quad * 4 + r) s[kt][r] = -1e30f;
              rowmax[r] = fmaxf(rowmax[r], s[kt][r]);
            }
          }
        } else {
#pragma unroll
          for (int kt = 0; kt < 4; ++kt)
#pragma unroll
            for (int r = 0; r < 4; ++r)
              rowmax[r] = fmaxf(rowmax[r], s[kt][r]);
        }
#pragma unroll
        for (int off = 1; off < 16; off <<= 1)
#pragma unroll
          for (int r = 0; r < 4; ++r)
            rowmax[r] = fmaxf(rowmax[r], __shfl_xor(rowmax[r], off, 64));
        float alpha[4], nms[4];
#pragma unroll
        for (int r = 0; r < 4; ++r) {
          const float mn = fmaxf(m_[m][r], rowmax[r]);
          alpha[r] = exp2f((m_[m][r] - mn) * sc);
          m_[m][r] = mn;
          nms[r] = -mn * sc;
        }
        // ---- P = exp2(s*sc - m*sc) -> sP (bf16) ----
#pragma unroll
        for (int kt = 0; kt < 4; ++kt)
#pragma unroll
          for (int r = 0; r < 4; ++r) {
            const float pv = exp2f(fmaf(s[kt][r], sc, nms[r]));
            sPw[(m * 16 + quad * 4 + r) * 72 + kt * 16 + l16] = (bf16)pv;
          }
        // ---- P fragments ----
        const bf16x8 ap0 = *(const bf16x8*)(&sPw[(m * 16 + l16) * 72 + quad * 8]);
        const bf16x8 ap1 = *(const bf16x8*)(&sPw[(m * 16 + l16) * 72 + 32 + quad * 8]);
        // ---- row-sum of P via MFMA with ones B-operand (same reg layout as s) ----
        f32x4 zs = {};
        zs = mfma_16x16x32(ap0, vones, zs);
        zs = mfma_16x16x32(ap1, vones, zs);
#pragma unroll
        for (int r = 0; r < 4; ++r) {
          l_[m][r] = l_[m][r] * alpha[r] + zs[r];
#pragma unroll
          for (int dt = 0; dt < 4; ++dt) oacc[m][dt][r] *= alpha[r];
        }
        // ---- PV ----
#pragma unroll
        for (int dt = 0; dt < 4; ++dt) {
          const bf16x8 bv0 = *(const bf16x8*)(&sVt[cur][(dt * 16 + l16) * 72 + quad * 8]);
          const bf16x8 bv1 = *(const bf16x8*)(&sVt[cur][(dt * 16 + l16) * 72 + 32 + quad * 8]);
          oacc[m][dt] = mfma_16x16x32(ap0, bv0, oacc[m][dt]);
          oacc[m][dt] = mfma_16x16x32(ap1, bv1, oacc[m][dt]);
        }
      }
    }

    // ---- write prefetched V into sVt[nxt] (loads arrived during compute) ----
    if (pre) {
#pragma unroll
      for (int r2 = 0; r2 < 2; ++r2) {
        const int cv = wave + 4 * r2;
#pragma unroll
        for (int e = 0; e < 8; ++e) sVt[nxt][(cv * 8 + e) * 72 + lane] = vpre[r2][e];
      }
    }
    __syncthreads();  // drains gload16 (K[nxt]) + makes sVt[nxt] visible
    cur = nxt;
  }

#pragma unroll
  for (int m = 0; m < 2; ++m)
#pragma unroll
    for (int r = 0; r < 4; ++r) {
      const float inv = 1.0f / l_[m][r];
      bf16* op = Og + (size_t)(b * TQ + qw + m * 16 + quad * 4 + r) * EMB + h * 64;
#pragma unroll
      for (int dt = 0; dt < 4; ++dt)
        op[dt * 16 + l16] = (bf16)(oacc[m][dt][r] * inv);
    }
}

// ---------------- host orchestration ----------------
extern "C" void kernel_launch(void* const* d_in, const int* in_sizes, int n_in,
                              void* d_out, int out_size, void* d_ws, size_t ws_size,
                              hipStream_t stream) {
  const float* enc  = (const float*)d_in[0];
  const float* dec  = (const float*)d_in[1];
  const float* ln1w = (const float*)d_in[2];
  const float* ln1b = (const float*)d_in[3];
  const float* ln2w = (const float*)d_in[4];
  const float* ln2b = (const float*)d_in[5];
  const float* ln3w = (const float*)d_in[6];
  const float* ln3b = (const float*)d_in[7];
  const float* Wq_s = (const float*)d_in[8];
  const float* Wk_s = (const float*)d_in[9];
  const float* Wv_s = (const float*)d_in[10];
  const float* Wo_s = (const float*)d_in[11];
  const float* bo_s = (const float*)d_in[12];
  const float* Wq_c = (const float*)d_in[13];
  const float* Wk_c = (const float*)d_in[14];
  const float* Wv_c = (const float*)d_in[15];
  const float* Wo_c = (const float*)d_in[16];
  const float* bo_c = (const float*)d_in[17];
  const float* W1   = (const float*)d_in[18];
  const float* b1   = (const float*)d_in[19];
  const float* W2   = (const float*)d_in[20];
  const float* b2   = (const float*)d_in[21];
  float* out = (float*)d_out;

  char* p = (char*)d_ws;
  auto take = [&](size_t bytes) {
    char* r = p;
    p += (bytes + 255) & ~(size_t)255;
    return (void*)r;
  };
  bf16* wqkvT = (bf16*)take((size_t)3 * EMB * EMB * 2);  // fused [3E, E] (q|k|v rows)
  bf16* woT   = (bf16*)take((size_t)EMB * EMB * 2);
  bf16* w1T   = (bf16*)take((size_t)EMB * FFN * 2);
  bf16* w2T   = (bf16*)take((size_t)FFN * EMB * 2);
  bf16* encb  = (bf16*)take((size_t)BATCH * SENC * EMB * 2);
  float* xbuf = (float*)take((size_t)MTOK * EMB * 4);
  bf16* nx    = (bf16*)take((size_t)MTOK * EMB * 2);
  bf16* qkvb  = (bf16*)take((size_t)MTOK * 3 * EMB * 2); // fused [M, 3E] (q|k|v cols)
  bf16* ab    = (bf16*)take((size_t)MTOK * EMB * 2);
  bf16* hb    = (bf16*)take((size_t)MTOK * FFN * 2);
  if ((size_t)((char*)p - (char*)d_ws) > ws_size) return;  // ws too small: fail loudly

  const int LD3 = 3 * EMB;

  // encoder -> bf16 (once); x = decoder_input
  {
    const int n4 = BATCH * SENC * EMB / 4;
    k_cvt<<<(n4 + 255) / 256, 256, 0, stream>>>(enc, encb, n4);
  }
  hipMemcpyAsync(xbuf, dec, (size_t)MTOK * EMB * 4, hipMemcpyDeviceToDevice, stream);

  auto trans = [&](const float* w, bf16* wt, int R, int C) {
    k_transpose<<<dim3(C / 32, R / 32), dim3(32, 8), 0, stream>>>(w, wt, R, C);
  };
  // 4 same-shape EMBxEMB weights in one launch
  auto trans4 = [&](const float* s0, const float* s1, const float* s2, const float* s3,
                    bf16* d0, bf16* d1, bf16* d2, bf16* d3) {
    k_transpose4<<<dim3(EMB / 32, EMB / 32, 4), dim3(32, 8), 0, stream>>>(
        s0, s1, s2, s3, d0, d1, d2, d3, EMB, EMB);
  };
  auto gemm0 = [&](const bf16* Ap, const bf16* Btp, bf16* op, int M, int N, int K,
                   int ldc) {
    k_gemm<0><<<dim3(N / 128, M / 128), 256, 0, stream>>>(Ap, Btp, M, N, K, ldc, op,
                                                          nullptr, nullptr, nullptr);
  };
  auto gemm_gelu = [&](const bf16* Ap, const bf16* Btp, bf16* op, const float* bi,
                       int M, int N, int K) {
    k_gemm<1><<<dim3(N / 128, M / 128), 256, 0, stream>>>(Ap, Btp, M, N, K, N, op,
                                                          nullptr, nullptr, bi);
  };
  auto gemm_res = [&](const bf16* Ap, const bf16* Btp, float* op, const float* rs,
                      const float* bi, int M, int N, int K) {
    k_gemm<2><<<dim3(N / 128, M / 128), 256, 0, stream>>>(Ap, Btp, M, N, K, N, nullptr,
                                                          op, rs, bi);
  };

  for (int l = 0; l < LAYERS; ++l) {
    const size_t wofs = (size_t)l * EMB * EMB;
    // ---- self attention ----
    k_layernorm<<<MTOK, 256, 0, stream>>>(xbuf, ln1w + l * EMB, ln1b + l * EMB, nx);
    trans4(Wq_s + wofs, Wk_s + wofs, Wv_s + wofs, Wo_s + wofs,
           wqkvT, wqkvT + (size_t)EMB * EMB, wqkvT + (size_t)2 * EMB * EMB, woT);
    // fused QKV projection: [M, 3E]
    gemm0(nx, wqkvT, qkvb, MTOK, 3 * EMB, EMB, LD3);
    k_attn<true><<<dim3(TDEC / 128, BATCH * NH), 256, 0, stream>>>(
        qkvb, qkvb + EMB, qkvb + 2 * EMB, ab, TDEC, TDEC, LD3);
    gemm_res(ab, woT, xbuf, xbuf, bo_s + l * EMB, MTOK, EMB, EMB);

    // ---- cross attention ----
    k_layernorm<<<MTOK, 256, 0, stream>>>(xbuf, ln2w + l * EMB, ln2b + l * EMB, nx);
    trans4(Wq_c + wofs, Wk_c + wofs, Wv_c + wofs, Wo_c + wofs,
           wqkvT, wqkvT + (size_t)EMB * EMB, wqkvT + (size_t)2 * EMB * EMB, woT);
    // Q over nx; fused K|V over encoder
    gemm0(nx, wqkvT, qkvb, MTOK, EMB, EMB, LD3);
    gemm0(encb, wqkvT + (size_t)EMB * EMB, qkvb + EMB, BATCH * SENC, 2 * EMB, EMB, LD3);
    k_attn<false><<<dim3(TDEC / 128, BATCH * NH), 256, 0, stream>>>(
        qkvb, qkvb + EMB, qkvb + 2 * EMB, ab, TDEC, SENC, LD3);
    gemm_res(ab, woT, xbuf, xbuf, bo_c + l * EMB, MTOK, EMB, EMB);

    // ---- FFN ----
    k_layernorm<<<MTOK, 256, 0, stream>>>(xbuf, ln3w + l * EMB, ln3b + l * EMB, nx);
    trans(W1 + (size_t)l * EMB * FFN, w1T, EMB, FFN);
    trans(W2 + (size_t)l * FFN * EMB, w2T, FFN, EMB);
    gemm_gelu(nx, w1T, hb, b1 + (size_t)l * FFN, MTOK, FFN, EMB);
    float* fout = (l == LAYERS - 1) ? out : xbuf;
    gemm_res(hb, w2T, fout, xbuf, b2 + (size_t)l * EMB, MTOK, EMB, FFN);
  }
}

// Round 4
// 4227.010 us; speedup vs baseline: 1.1547x; 1.0867x over previous
//
#include <hip/hip_runtime.h>
#include <cstdint>

typedef __bf16 bf16;
typedef __bf16 bf16x8 __attribute__((ext_vector_type(8)));
typedef __bf16 bf16x4 __attribute__((ext_vector_type(4)));
typedef float f32x4 __attribute__((ext_vector_type(4)));

static_assert(sizeof(bf16) == 2, "bf16 size");

constexpr int LAYERS = 6;
constexpr int BATCH  = 8;
constexpr int TDEC   = 1024;
constexpr int SENC   = 1024;
constexpr int EMB    = 1024;
constexpr int NH     = 16;
constexpr int FFN    = 4096;
constexpr int MTOK   = BATCH * TDEC;  // 8192

typedef __attribute__((address_space(1))) void gvoid;
typedef __attribute__((address_space(3))) void lvoid;

// async global->LDS, 16B per lane; LDS dest = wave-uniform base + lane*16
__device__ __forceinline__ void gload16(const void* g, void* l) {
  __builtin_amdgcn_global_load_lds((gvoid*)(uintptr_t)g,
                                   (lvoid*)(uint32_t)(uintptr_t)l,
                                   16, 0, 0);
}

__device__ __forceinline__ f32x4 mfma_16x16x32(bf16x8 a, bf16x8 b, f32x4 c) {
  return __builtin_amdgcn_mfma_f32_16x16x32_bf16(a, b, c, 0, 0, 0);
}

// ---------------- elementwise: fp32 -> bf16 convert ----------------
__global__ void k_cvt(const float* __restrict__ in, bf16* __restrict__ outp, int n4) {
  int i = blockIdx.x * 256 + threadIdx.x;
  if (i < n4) {
    float4 v = ((const float4*)in)[i];
    bf16x4 o;
    o[0] = (bf16)v.x; o[1] = (bf16)v.y; o[2] = (bf16)v.z; o[3] = (bf16)v.w;
    ((bf16x4*)outp)[i] = o;
  }
}

// ---------------- transpose fp32 [R,C] -> bf16 [C,R] ----------------
__launch_bounds__(256)
__global__ void k_transpose(const float* __restrict__ in, bf16* __restrict__ outp,
                            int R, int C) {
  __shared__ float tile[32][33];
  const int tx = threadIdx.x, ty = threadIdx.y;
  const int r0 = blockIdx.y * 32, c0 = blockIdx.x * 32;
#pragma unroll
  for (int i = 0; i < 32; i += 8)
    tile[ty + i][tx] = in[(size_t)(r0 + ty + i) * C + c0 + tx];
  __syncthreads();
#pragma unroll
  for (int i = 0; i < 32; i += 8)
    outp[(size_t)(c0 + ty + i) * R + r0 + tx] = (bf16)tile[tx][ty + i];
}

// batched 4-matrix transpose (same shape), select by blockIdx.z
__launch_bounds__(256)
__global__ void k_transpose4(const float* __restrict__ s0, const float* __restrict__ s1,
                             const float* __restrict__ s2, const float* __restrict__ s3,
                             bf16* __restrict__ d0, bf16* __restrict__ d1,
                             bf16* __restrict__ d2, bf16* __restrict__ d3,
                             int R, int C) {
  const int z = blockIdx.z;
  const float* in = (z == 0) ? s0 : (z == 1) ? s1 : (z == 2) ? s2 : s3;
  bf16* outp      = (z == 0) ? d0 : (z == 1) ? d1 : (z == 2) ? d2 : d3;
  __shared__ float tile[32][33];
  const int tx = threadIdx.x, ty = threadIdx.y;
  const int r0 = blockIdx.y * 32, c0 = blockIdx.x * 32;
#pragma unroll
  for (int i = 0; i < 32; i += 8)
    tile[ty + i][tx] = in[(size_t)(r0 + ty + i) * C + c0 + tx];
  __syncthreads();
#pragma unroll
  for (int i = 0; i < 32; i += 8)
    outp[(size_t)(c0 + ty + i) * R + r0 + tx] = (bf16)tile[tx][ty + i];
}

// ---------------- LayerNorm fp32 -> bf16, row = 1024 ----------------
__launch_bounds__(256)
__global__ void k_layernorm(const float* __restrict__ x, const float* __restrict__ w,
                            const float* __restrict__ bb, bf16* __restrict__ outp) {
  const int row = blockIdx.x;
  const int t = threadIdx.x;
  const float4 v = ((const float4*)(x + (size_t)row * EMB))[t];
  float s = v.x + v.y + v.z + v.w;
  __shared__ float red[4];
#pragma unroll
  for (int off = 32; off > 0; off >>= 1) s += __shfl_down(s, off, 64);
  if ((t & 63) == 0) red[t >> 6] = s;
  __syncthreads();
  const float mean = (red[0] + red[1] + red[2] + red[3]) * (1.0f / EMB);
  const float dx = v.x - mean, dy = v.y - mean, dz = v.z - mean, dw = v.w - mean;
  float ss = dx * dx + dy * dy + dz * dz + dw * dw;
  __syncthreads();
#pragma unroll
  for (int off = 32; off > 0; off >>= 1) ss += __shfl_down(ss, off, 64);
  if ((t & 63) == 0) red[t >> 6] = ss;
  __syncthreads();
  const float var = (red[0] + red[1] + red[2] + red[3]) * (1.0f / EMB);
  const float rstd = rsqrtf(var + 1e-5f);
  const float4 wv = ((const float4*)w)[t];
  const float4 bv = ((const float4*)bb)[t];
  bf16x4 o;
  o[0] = (bf16)(dx * rstd * wv.x + bv.x);
  o[1] = (bf16)(dy * rstd * wv.y + bv.y);
  o[2] = (bf16)(dz * rstd * wv.z + bv.z);
  o[3] = (bf16)(dw * rstd * wv.w + bv.w);
  *(bf16x4*)(outp + (size_t)row * EMB + t * 4) = o;
}

// ---------------- GEMM: C[M,N] = A[M,K] @ Bt[N,K]^T, output ld = ldc ----------
// EPI 0: bf16 out. EPI 1: bf16 out = gelu(acc + bias). EPI 2: fp32 out = res + acc + bias.
// T1 XCD swizzle: contiguous block-id chunk per XCD (bijective when nwg%8==0).
// T3+T4 pipeline: 3 LDS buffers, 2-deep gload16 prefetch, counted vmcnt(4)
// (never 0 in steady state) + raw s_barrier — one barrier per K-step, staging
// latency hidden under the previous step's ds_read+MFMA.
// Per-wave vmcnt(4) retires that wave's own tile-(t+1) stage (its oldest 4 loads);
// the barrier then guarantees ALL waves' t+1 loads landed before anyone reads t+1.
template <int EPI>
__launch_bounds__(256)
__global__ void k_gemm(const bf16* __restrict__ A, const bf16* __restrict__ Bt,
                       int M, int N, int K, int ldc,
                       bf16* __restrict__ outb, float* __restrict__ outf,
                       const float* __restrict__ res, const float* __restrict__ bias) {
  __shared__ __align__(16) bf16 sA[3][128 * 32];
  __shared__ __align__(16) bf16 sB[3][128 * 32];
  const int tid = threadIdx.x;
  const int wave = tid >> 6, lane = tid & 63;
  const int quad = lane >> 4, l16 = lane & 15;
  const int wm = wave >> 1, wn = wave & 1;

  // XCD-aware block swizzle
  int bid = blockIdx.y * gridDim.x + blockIdx.x;
  const int nwg = gridDim.x * gridDim.y;
  if ((nwg & 7) == 0) {
    const int q = nwg >> 3;
    bid = (bid & 7) * q + (bid >> 3);
  }
  const int bn = bid % gridDim.x;
  const int bm = bid / gridDim.x;

  f32x4 acc[4][4] = {};

  const int srow = wave * 16 + (lane >> 2);
  const int scol = (lane & 3) * 8;
  const bf16* Ag = A  + (size_t)(bm * 128 + srow) * K + scol;
  const bf16* Bg = Bt + (size_t)(bn * 128 + srow) * K + scol;

  auto stage = [&](int buf, int kt) {
    const bf16* ag = Ag + kt * 32;
    const bf16* bg = Bg + kt * 32;
    gload16(ag,                  &sA[buf][(wave * 16) * 32]);
    gload16(ag + (size_t)64 * K, &sA[buf][(wave * 16 + 64) * 32]);
    gload16(bg,                  &sB[buf][(wave * 16) * 32]);
    gload16(bg + (size_t)64 * K, &sB[buf][(wave * 16 + 64) * 32]);
  };

  const int nk = K >> 5;
  // ---- prologue: stage tiles 0 and 1 ----
  stage(0, 0);
  if (nk > 1) {
    stage(1, 1);
    asm volatile("s_waitcnt vmcnt(4)" ::: "memory");  // tile 0 landed
  } else {
    asm volatile("s_waitcnt vmcnt(0)" ::: "memory");
  }
  __builtin_amdgcn_s_barrier();

  int cur = 0;
  for (int kt = 0; kt < nk; ++kt) {
    int nxt2 = cur + 2; if (nxt2 >= 3) nxt2 -= 3;
    if (kt + 2 < nk) stage(nxt2, kt + 2);

    bf16x8 af[4], bfv[4];
    const bf16* pa = &sA[cur][(wm * 64 + l16) * 32 + quad * 8];
    const bf16* pb = &sB[cur][(wn * 64 + l16) * 32 + quad * 8];
#pragma unroll
    for (int i = 0; i < 4; ++i) af[i] = *(const bf16x8*)(pa + i * 16 * 32);
#pragma unroll
    for (int i = 0; i < 4; ++i) bfv[i] = *(const bf16x8*)(pb + i * 16 * 32);
#pragma unroll
    for (int i = 0; i < 4; ++i)
#pragma unroll
      for (int j = 0; j < 4; ++j)
        acc[i][j] = mfma_16x16x32(af[i], bfv[j], acc[i][j]);

    if (kt + 2 < nk) {
      asm volatile("s_waitcnt vmcnt(4)" ::: "memory");  // tile kt+1 landed
      __builtin_amdgcn_s_barrier();
    } else if (kt + 1 < nk) {
      asm volatile("s_waitcnt vmcnt(0)" ::: "memory");  // last prefetch landed
      __builtin_amdgcn_s_barrier();
    }
    cur = (cur + 1 == 3) ? 0 : cur + 1;
  }

  const int row0 = bm * 128 + wm * 64;
  const int col0 = bn * 128 + wn * 64;
#pragma unroll
  for (int j = 0; j < 4; ++j) {
    const int c = col0 + j * 16 + l16;
    const float bv = (EPI >= 1) ? bias[c] : 0.0f;
#pragma unroll
    for (int i = 0; i < 4; ++i) {
#pragma unroll
      for (int r = 0; r < 4; ++r) {
        const size_t rr = (size_t)(row0 + i * 16 + quad * 4 + r);
        float v = acc[i][j][r];
        if (EPI == 0) {
          outb[rr * ldc + c] = (bf16)v;
        } else if (EPI == 1) {
          v += bv;
          // gelu tanh-approx: 0.5v(1+tanh(u)) == v / (1 + exp2(-2u*log2e))
          const float u = 0.7978845608028654f * (v + 0.044715f * v * v * v);
          const float g = v / (1.0f + exp2f(u * -2.8853900817779268f));
          outb[rr * ldc + c] = (bf16)g;
        } else {
          outf[rr * ldc + c] = res[rr * ldc + c] + v + bv;
        }
      }
    }
  }
}

// ---------------- flash attention v2, pipelined ----------------
// 128 q-rows / block (wave w: rows q0+32w..+31, two 16-row m-subtiles),
// 64-key tiles, DOUBLE-BUFFERED K/V with one barrier per tile:
//   prefetch K[j+1] (gload16) + V[j+1] (regs) -> compute tile j -> write V regs
//   -> barrier. sK XOR-swizzled; sVt/sP stride-72.
// Row-sum of P computed by MFMA with constant ones B-fragment (no shuffles).
// Causal mask ops only on diagonal-straddling tiles.
// T1 swizzle: each XCD owns gridDim.y/8 whole heads.
// grid: (TQ/128, B*NH), block 256.
template <bool CAUSAL>
__launch_bounds__(256)
__global__ void k_attn(const bf16* __restrict__ Q, const bf16* __restrict__ Kg,
                       const bf16* __restrict__ Vg, bf16* __restrict__ Og,
                       int TQ, int TK, int ld) {
  __shared__ __align__(16) bf16 sK[2][64 * 64];   // [buf][key][d], XOR-swizzled
  __shared__ __align__(16) bf16 sVt[2][64 * 72];  // [buf][d][key], stride 72
  __shared__ __align__(16) bf16 sP[4][32 * 72];   // per wave, [q_local][key]
  const int tid = threadIdx.x;
  const int wave = tid >> 6, lane = tid & 63;
  const int quad = lane >> 4, l16 = lane & 15;

  // XCD-aware remap: cluster all q-tiles of a head on one XCD
  int bx = blockIdx.x, by = blockIdx.y;
  {
    const int nwg = gridDim.x * gridDim.y;
    if ((nwg & 7) == 0 && (gridDim.y & 7) == 0) {
      const int d = by * gridDim.x + bx;
      const int xcd = d & 7, idx = d >> 3;
      const int hpx = gridDim.y >> 3;  // heads per XCD
      by = xcd * hpx + idx / gridDim.x;
      bx = idx % gridDim.x;
    }
  }
  const int b = by >> 4;   // NH == 16
  const int h = by & 15;
  const int qt = CAUSAL ? (gridDim.x - 1 - bx) : bx;
  const int q0 = qt * 128;
  const int qw = q0 + wave * 32;

  const bf16* Qbase = Q + (size_t)(b * TQ) * ld + h * 64;
  const bf16* Kbase = Kg + (size_t)(b * TK) * ld + h * 64;
  const bf16* Vbase = Vg + (size_t)(b * TK) * ld + h * 64;

  // Q fragments: aq[m][c] covers rows qw+m*16+l16, d = c*32 + quad*8 .. +7
  bf16x8 aq[2][2];
#pragma unroll
  for (int m = 0; m < 2; ++m) {
    const bf16* qp = Qbase + (size_t)(qw + m * 16 + l16) * ld + quad * 8;
    aq[m][0] = *(const bf16x8*)(qp);
    aq[m][1] = *(const bf16x8*)(qp + 32);
  }

  bf16x8 vones;
#pragma unroll
  for (int e = 0; e < 8; ++e) vones[e] = (bf16)1.0f;

  f32x4 oacc[2][4] = {};
  float m_[2][4], l_[2][4];
#pragma unroll
  for (int m = 0; m < 2; ++m)
#pragma unroll
    for (int r = 0; r < 4; ++r) { m_[m][r] = -1e30f; l_[m][r] = 0.0f; }

  const int srow = lane >> 3;      // 0..7 (row within 8-row staging group)
  const int schunk = lane & 7;     // physical 16B chunk
  bf16* sPw = &sP[wave][0];

  const float sc = 0.125f * 1.44269504088896f;  // 1/sqrt(64) * log2(e)
  const int nj = CAUSAL ? (q0 >> 6) + 2 : (TK >> 6);

  // ---- prologue: stage tile 0 into buffer 0 ----
#pragma unroll
  for (int r2 = 0; r2 < 2; ++r2) {
    const int rowt = (wave + 4 * r2) * 8 + srow;
    const int gchunk = schunk ^ (rowt & 7);
    gload16(Kbase + (size_t)rowt * ld + gchunk * 8,
            &sK[0][(wave + 4 * r2) * 8 * 64]);
  }
#pragma unroll
  for (int r2 = 0; r2 < 2; ++r2) {
    const int cv = wave + 4 * r2;
    const bf16x8 vv = *(const bf16x8*)(Vbase + (size_t)lane * ld + cv * 8);
#pragma unroll
    for (int e = 0; e < 8; ++e) sVt[0][(cv * 8 + e) * 72 + lane] = vv[e];
  }
  __syncthreads();

  int cur = 0;
  for (int j = 0; j < nj; ++j) {
    const int nxt = cur ^ 1;
    const int k0 = j * 64;
    const bool pre = (j + 1 < nj);
    bf16x8 vpre[2];
    // ---- prefetch tile j+1: K -> sK[nxt] (async DMA), V -> regs ----
    if (pre) {
      const int k0n = k0 + 64;
#pragma unroll
      for (int r2 = 0; r2 < 2; ++r2) {
        const int rowt = (wave + 4 * r2) * 8 + srow;
        const int gchunk = schunk ^ (rowt & 7);
        gload16(Kbase + (size_t)(k0n + rowt) * ld + gchunk * 8,
                &sK[nxt][(wave + 4 * r2) * 8 * 64]);
      }
#pragma unroll
      for (int r2 = 0; r2 < 2; ++r2)
        vpre[r2] = *(const bf16x8*)(Vbase + (size_t)(k0n + lane) * ld +
                                    (wave + 4 * r2) * 8);
    }

    const bool active = !CAUSAL || (k0 <= qw + 31);
    if (active) {
#pragma unroll
      for (int m = 0; m < 2; ++m) {
        // ---- QK^T: scores s[kt][r] = S[row=m*16+quad*4+r][key=kt*16+l16] ----
        f32x4 s[4];
#pragma unroll
        for (int kt = 0; kt < 4; ++kt) {
          const int krow = kt * 16 + l16;
          const int p0 = (quad ^ (l16 & 7)) * 8;
          const int p1 = ((quad + 4) ^ (l16 & 7)) * 8;
          const bf16x8 bk0 = *(const bf16x8*)(&sK[cur][krow * 64 + p0]);
          const bf16x8 bk1 = *(const bf16x8*)(&sK[cur][krow * 64 + p1]);
          f32x4 z = {};
          z = mfma_16x16x32(aq[m][0], bk0, z);
          z = mfma_16x16x32(aq[m][1], bk1, z);
          s[kt] = z;
        }
        // ---- causal mask only on diagonal-straddling tiles + row max ----
        const int row_base = qw + m * 16;
        float rowmax[4] = {-1e30f, -1e30f, -1e30f, -1e30f};
        if (CAUSAL && (k0 + 63 > row_base)) {
#pragma unroll
          for (int kt = 0; kt < 4; ++kt) {
            const int key = k0 + kt * 16 + l16;
#pragma unroll
            for (int r = 0; r < 4; ++r) {
              if (key > row_base + quad * 4 + r) s[kt][r] = -1e30f;
              rowmax[r] = fmaxf(rowmax[r], s[kt][r]);
            }
          }
        } else {
#pragma unroll
          for (int kt = 0; kt < 4; ++kt)
#pragma unroll
            for (int r = 0; r < 4; ++r)
              rowmax[r] = fmaxf(rowmax[r], s[kt][r]);
        }
#pragma unroll
        for (int off = 1; off < 16; off <<= 1)
#pragma unroll
          for (int r = 0; r < 4; ++r)
            rowmax[r] = fmaxf(rowmax[r], __shfl_xor(rowmax[r], off, 64));
        float alpha[4], nms[4];
#pragma unroll
        for (int r = 0; r < 4; ++r) {
          const float mn = fmaxf(m_[m][r], rowmax[r]);
          alpha[r] = exp2f((m_[m][r] - mn) * sc);
          m_[m][r] = mn;
          nms[r] = -mn * sc;
        }
        // ---- P = exp2(s*sc - m*sc) -> sP (bf16) ----
#pragma unroll
        for (int kt = 0; kt < 4; ++kt)
#pragma unroll
          for (int r = 0; r < 4; ++r) {
            const float pv = exp2f(fmaf(s[kt][r], sc, nms[r]));
            sPw[(m * 16 + quad * 4 + r) * 72 + kt * 16 + l16] = (bf16)pv;
          }
        // ---- P fragments ----
        const bf16x8 ap0 = *(const bf16x8*)(&sPw[(m * 16 + l16) * 72 + quad * 8]);
        const bf16x8 ap1 = *(const bf16x8*)(&sPw[(m * 16 + l16) * 72 + 32 + quad * 8]);
        // ---- row-sum of P via MFMA with ones B-operand (same reg layout as s) ----
        f32x4 zs = {};
        zs = mfma_16x16x32(ap0, vones, zs);
        zs = mfma_16x16x32(ap1, vones, zs);
#pragma unroll
        for (int r = 0; r < 4; ++r) {
          l_[m][r] = l_[m][r] * alpha[r] + zs[r];
#pragma unroll
          for (int dt = 0; dt < 4; ++dt) oacc[m][dt][r] *= alpha[r];
        }
        // ---- PV ----
#pragma unroll
        for (int dt = 0; dt < 4; ++dt) {
          const bf16x8 bv0 = *(const bf16x8*)(&sVt[cur][(dt * 16 + l16) * 72 + quad * 8]);
          const bf16x8 bv1 = *(const bf16x8*)(&sVt[cur][(dt * 16 + l16) * 72 + 32 + quad * 8]);
          oacc[m][dt] = mfma_16x16x32(ap0, bv0, oacc[m][dt]);
          oacc[m][dt] = mfma_16x16x32(ap1, bv1, oacc[m][dt]);
        }
      }
    }

    // ---- write prefetched V into sVt[nxt] (loads arrived during compute) ----
    if (pre) {
#pragma unroll
      for (int r2 = 0; r2 < 2; ++r2) {
        const int cv = wave + 4 * r2;
#pragma unroll
        for (int e = 0; e < 8; ++e) sVt[nxt][(cv * 8 + e) * 72 + lane] = vpre[r2][e];
      }
    }
    __syncthreads();  // drains gload16 (K[nxt]) + makes sVt[nxt] visible
    cur = nxt;
  }

#pragma unroll
  for (int m = 0; m < 2; ++m)
#pragma unroll
    for (int r = 0; r < 4; ++r) {
      const float inv = 1.0f / l_[m][r];
      bf16* op = Og + (size_t)(b * TQ + qw + m * 16 + quad * 4 + r) * EMB + h * 64;
#pragma unroll
      for (int dt = 0; dt < 4; ++dt)
        op[dt * 16 + l16] = (bf16)(oacc[m][dt][r] * inv);
    }
}

// ---------------- host orchestration ----------------
extern "C" void kernel_launch(void* const* d_in, const int* in_sizes, int n_in,
                              void* d_out, int out_size, void* d_ws, size_t ws_size,
                              hipStream_t stream) {
  const float* enc  = (const float*)d_in[0];
  const float* dec  = (const float*)d_in[1];
  const float* ln1w = (const float*)d_in[2];
  const float* ln1b = (const float*)d_in[3];
  const float* ln2w = (const float*)d_in[4];
  const float* ln2b = (const float*)d_in[5];
  const float* ln3w = (const float*)d_in[6];
  const float* ln3b = (const float*)d_in[7];
  const float* Wq_s = (const float*)d_in[8];
  const float* Wk_s = (const float*)d_in[9];
  const float* Wv_s = (const float*)d_in[10];
  const float* Wo_s = (const float*)d_in[11];
  const float* bo_s = (const float*)d_in[12];
  const float* Wq_c = (const float*)d_in[13];
  const float* Wk_c = (const float*)d_in[14];
  const float* Wv_c = (const float*)d_in[15];
  const float* Wo_c = (const float*)d_in[16];
  const float* bo_c = (const float*)d_in[17];
  const float* W1   = (const float*)d_in[18];
  const float* b1   = (const float*)d_in[19];
  const float* W2   = (const float*)d_in[20];
  const float* b2   = (const float*)d_in[21];
  float* out = (float*)d_out;

  char* p = (char*)d_ws;
  auto take = [&](size_t bytes) {
    char* r = p;
    p += (bytes + 255) & ~(size_t)255;
    return (void*)r;
  };
  bf16* wqkvT = (bf16*)take((size_t)3 * EMB * EMB * 2);  // fused [3E, E] (q|k|v rows)
  bf16* woT   = (bf16*)take((size_t)EMB * EMB * 2);
  bf16* w1T   = (bf16*)take((size_t)EMB * FFN * 2);
  bf16* w2T   = (bf16*)take((size_t)FFN * EMB * 2);
  bf16* encb  = (bf16*)take((size_t)BATCH * SENC * EMB * 2);
  float* xbuf = (float*)take((size_t)MTOK * EMB * 4);
  bf16* nx    = (bf16*)take((size_t)MTOK * EMB * 2);
  bf16* qkvb  = (bf16*)take((size_t)MTOK * 3 * EMB * 2); // fused [M, 3E] (q|k|v cols)
  bf16* ab    = (bf16*)take((size_t)MTOK * EMB * 2);
  bf16* hb    = (bf16*)take((size_t)MTOK * FFN * 2);
  if ((size_t)((char*)p - (char*)d_ws) > ws_size) return;  // ws too small: fail loudly

  const int LD3 = 3 * EMB;

  // encoder -> bf16 (once); x = decoder_input
  {
    const int n4 = BATCH * SENC * EMB / 4;
    k_cvt<<<(n4 + 255) / 256, 256, 0, stream>>>(enc, encb, n4);
  }
  hipMemcpyAsync(xbuf, dec, (size_t)MTOK * EMB * 4, hipMemcpyDeviceToDevice, stream);

  auto trans = [&](const float* w, bf16* wt, int R, int C) {
    k_transpose<<<dim3(C / 32, R / 32), dim3(32, 8), 0, stream>>>(w, wt, R, C);
  };
  // 4 same-shape EMBxEMB weights in one launch
  auto trans4 = [&](const float* s0, const float* s1, const float* s2, const float* s3,
                    bf16* d0, bf16* d1, bf16* d2, bf16* d3) {
    k_transpose4<<<dim3(EMB / 32, EMB / 32, 4), dim3(32, 8), 0, stream>>>(
        s0, s1, s2, s3, d0, d1, d2, d3, EMB, EMB);
  };
  auto gemm0 = [&](const bf16* Ap, const bf16* Btp, bf16* op, int M, int N, int K,
                   int ldc) {
    k_gemm<0><<<dim3(N / 128, M / 128), 256, 0, stream>>>(Ap, Btp, M, N, K, ldc, op,
                                                          nullptr, nullptr, nullptr);
  };
  auto gemm_gelu = [&](const bf16* Ap, const bf16* Btp, bf16* op, const float* bi,
                       int M, int N, int K) {
    k_gemm<1><<<dim3(N / 128, M / 128), 256, 0, stream>>>(Ap, Btp, M, N, K, N, op,
                                                          nullptr, nullptr, bi);
  };
  auto gemm_res = [&](const bf16* Ap, const bf16* Btp, float* op, const float* rs,
                      const float* bi, int M, int N, int K) {
    k_gemm<2><<<dim3(N / 128, M / 128), 256, 0, stream>>>(Ap, Btp, M, N, K, N, nullptr,
                                                          op, rs, bi);
  };

  for (int l = 0; l < LAYERS; ++l) {
    const size_t wofs = (size_t)l * EMB * EMB;
    // ---- self attention ----
    k_layernorm<<<MTOK, 256, 0, stream>>>(xbuf, ln1w + l * EMB, ln1b + l * EMB, nx);
    trans4(Wq_s + wofs, Wk_s + wofs, Wv_s + wofs, Wo_s + wofs,
           wqkvT, wqkvT + (size_t)EMB * EMB, wqkvT + (size_t)2 * EMB * EMB, woT);
    // fused QKV projection: [M, 3E]
    gemm0(nx, wqkvT, qkvb, MTOK, 3 * EMB, EMB, LD3);
    k_attn<true><<<dim3(TDEC / 128, BATCH * NH), 256, 0, stream>>>(
        qkvb, qkvb + EMB, qkvb + 2 * EMB, ab, TDEC, TDEC, LD3);
    gemm_res(ab, woT, xbuf, xbuf, bo_s + l * EMB, MTOK, EMB, EMB);

    // ---- cross attention ----
    k_layernorm<<<MTOK, 256, 0, stream>>>(xbuf, ln2w + l * EMB, ln2b + l * EMB, nx);
    trans4(Wq_c + wofs, Wk_c + wofs, Wv_c + wofs, Wo_c + wofs,
           wqkvT, wqkvT + (size_t)EMB * EMB, wqkvT + (size_t)2 * EMB * EMB, woT);
    // Q over nx; fused K|V over encoder
    gemm0(nx, wqkvT, qkvb, MTOK, EMB, EMB, LD3);
    gemm0(encb, wqkvT + (size_t)EMB * EMB, qkvb + EMB, BATCH * SENC, 2 * EMB, EMB, LD3);
    k_attn<false><<<dim3(TDEC / 128, BATCH * NH), 256, 0, stream>>>(
        qkvb, qkvb + EMB, qkvb + 2 * EMB, ab, TDEC, SENC, LD3);
    gemm_res(ab, woT, xbuf, xbuf, bo_c + l * EMB, MTOK, EMB, EMB);

    // ---- FFN ----
    k_layernorm<<<MTOK, 256, 0, stream>>>(xbuf, ln3w + l * EMB, ln3b + l * EMB, nx);
    trans(W1 + (size_t)l * EMB * FFN, w1T, EMB, FFN);
    trans(W2 + (size_t)l * FFN * EMB, w2T, FFN, EMB);
    gemm_gelu(nx, w1T, hb, b1 + (size_t)l * FFN, MTOK, FFN, EMB);
    float* fout = (l == LAYERS - 1) ? out : xbuf;
    gemm_res(hb, w2T, fout, xbuf, b2 + (size_t)l * EMB, MTOK, EMB, FFN);
  }
}